// Round 3
// baseline (202.894 us; speedup 1.0000x reference)
//
#include <hip/hip_runtime.h>
#include <stdint.h>

// AttentionHead: out = softmax(QK^T/sqrt(dk) - 1e15*mask) @ V, Q/K/V = inputs @ W{q,k,v}
// B=4 S=2048 E=1024 D=128. bf16 MFMA; swapped-QK^T flash attention, register-direct K/V.

#define SEQ   2048
#define EDIM  1024
#define DDIM  128
#define QSCALE 0.08838834764831845f   // 1/sqrt(128)

typedef unsigned short u16;
typedef unsigned int   u32;
using short8 = __attribute__((ext_vector_type(8))) short;   // 8 x bf16 (4 VGPR) MFMA frag
using f32x4  = __attribute__((ext_vector_type(4))) float;
using int4v  = __attribute__((ext_vector_type(4))) int;

__device__ __forceinline__ u16 f2bf(float x) {              // f32 -> bf16 RNE
    uint32_t u = __float_as_uint(x);
    return (u16)((u + 0x7fffu + ((u >> 16) & 1u)) >> 16);
}

// async global->LDS 16B per lane; LDS dst = wave-uniform base + lane*16 (linear).
__device__ __forceinline__ void gld16(const void* gsrc, void* lds_dst) {
    __builtin_amdgcn_global_load_lds(
        (const __attribute__((address_space(1))) uint32_t*)(uintptr_t)gsrc,
        (__attribute__((address_space(3))) uint32_t*)(uint32_t)(uintptr_t)lds_dst,
        16, 0, 0);
}

// ---------------- kernel 1: prep = mask bit-pack (coalesced) + W transpose ---------------
// blocks [0,2048): pack 8192 mask values -> 256 u32 words each. blocks [2048,2144): W->Wt.
__global__ __launch_bounds__(256) void prep_kernel(
    const int* __restrict__ mask,
    const float* __restrict__ Wq, const float* __restrict__ Wk, const float* __restrict__ Wv,
    u32* __restrict__ Mbits, u16* __restrict__ Wt)
{
    __shared__ u32 nib32[2048];            // 8KB, transposed+swizzled nibble store
    __shared__ u16 tl[64][65];
    const int bx = blockIdx.x;
    const int tid = threadIdx.x;
    if (bx < 2048) {
        const int* src = mask + (size_t)bx * 8192;
#pragma unroll
        for (int it = 0; it < 8; ++it) {
            const int idx = it * 256 + tid;                 // nibble id 0..2047
            const int4v v = *(const int4v*)(src + idx * 4); // 16B/lane contiguous
            const u32 nb = (v[0] != 0 ? 1u : 0u) | (v[1] != 0 ? 2u : 0u)
                         | (v[2] != 0 ? 4u : 0u) | (v[3] != 0 ? 8u : 0u);
            nib32[(idx & 7) * 256 + ((idx >> 3) ^ ((idx & 7) << 2))] = nb;
        }
        __syncthreads();
        u32 word = 0;
#pragma unroll
        for (int j = 0; j < 8; ++j)
            word |= (nib32[j * 256 + (tid ^ (j << 2))] & 0xFu) << (4 * j);
        Mbits[bx * 256 + tid] = word;
    } else {
        const int t = bx - 2048;                            // 96 = 3 mats * 32 tiles
        const int wsel = t >> 5;
        const int tile = t & 31;
        const int k0 = (tile >> 1) * 64;
        const int n0 = (tile & 1) * 64;
        const float* W = (wsel == 0) ? Wq : ((wsel == 1) ? Wk : Wv);
#pragma unroll
        for (int it = 0; it < 16; ++it) {
            const int idx = it * 256 + tid;
            const int r = idx >> 6, c = idx & 63;
            tl[c][r] = f2bf(W[(size_t)(k0 + r) * DDIM + n0 + c]);
        }
        __syncthreads();
        u16* Wtp = Wt + (size_t)wsel * DDIM * EDIM;
#pragma unroll
        for (int it = 0; it < 16; ++it) {
            const int idx = it * 256 + tid;
            const int r = idx >> 6, c = idx & 63;
            Wtp[(size_t)(n0 + r) * EDIM + k0 + c] = tl[r][c];
        }
    }
}

// ---------------- kernel 2: projections. 768 blocks, tile 32m x 128n, BK=64 --------------
// 4 waves, wave w -> 32m x 32n (n0 = w*32). XCD swizzle keeps one A-panel's 3 wm on one XCD.
__global__ __launch_bounds__(256, 3) void proj_kernel(
    const float* __restrict__ Ain, const u16* __restrict__ Wtb,
    u16* __restrict__ Qb, u16* __restrict__ Kb, u16* __restrict__ Vtb)
{
    __shared__ __align__(16) uint8_t smem[20480];   // A 4KB @0, B 16KB @4096 (swizzled rows)
    const int tid = threadIdx.x;
    const int w = tid >> 6, lane = tid & 63;
    const int lq = lane & 15, lg = lane >> 4;

    const int bid = blockIdx.x;                      // 768 = 8 xcd * 96
    const int wg = (bid & 7) * 96 + (bid >> 3);
    const int wm = wg % 3;
    const int m0 = (wg / 3) * 32;
    const u16* Wt = Wtb + (size_t)wm * DDIM * EDIM;

    f32x4 acc[2][2] = {};

#pragma unroll 1
    for (int kt = 0; kt < 16; ++kt) {
        const int k0 = kt * 64;
        // B: Wt tile [128 n][64 k] via gld16, linear dest + inverse-swizzled source
#pragma unroll
        for (int i = 0; i < 4; ++i) {
            const int G = i * 256 + tid;
            const int n = G >> 3, c = G & 7;
            gld16(Wt + (size_t)n * EDIM + k0 + ((c ^ (n & 7)) << 3),
                  smem + 4096 + i * 4096 + w * 1024);
        }
        // A: [32 m][64 k] f32 -> bf16 reg-staged, swizzled ds_write_b128
        {
            const int row = tid >> 3, c = tid & 7;
            const float* s2 = Ain + (size_t)(m0 + row) * EDIM + k0 + ((c ^ (row & 7)) << 3);
            const f32x4 a0 = *(const f32x4*)s2;
            const f32x4 a1 = *(const f32x4*)(s2 + 4);
            short8 v;
            v[0] = (short)f2bf(a0[0]); v[1] = (short)f2bf(a0[1]);
            v[2] = (short)f2bf(a0[2]); v[3] = (short)f2bf(a0[3]);
            v[4] = (short)f2bf(a1[0]); v[5] = (short)f2bf(a1[1]);
            v[6] = (short)f2bf(a1[2]); v[7] = (short)f2bf(a1[3]);
            *(short8*)(smem + row * 128 + (c << 4)) = v;
        }
        __syncthreads();
#pragma unroll
        for (int ks = 0; ks < 2; ++ks) {
            short8 af[2], bfv[2];
#pragma unroll
            for (int mf = 0; mf < 2; ++mf) {
                const int arow = mf * 16 + lq;
                af[mf] = *(const short8*)(smem + arow * 128 + ((((ks << 2) + lg) ^ (arow & 7)) << 4));
            }
#pragma unroll
            for (int nf = 0; nf < 2; ++nf) {
                const int brow = w * 32 + nf * 16 + lq;
                bfv[nf] = *(const short8*)(smem + 4096 + brow * 128 + ((((ks << 2) + lg) ^ (brow & 7)) << 4));
            }
#pragma unroll
            for (int mf = 0; mf < 2; ++mf)
#pragma unroll
                for (int nf = 0; nf < 2; ++nf)
                    acc[mf][nf] = __builtin_amdgcn_mfma_f32_16x16x32_bf16(af[mf], bfv[nf], acc[mf][nf], 0, 0, 0);
        }
        __syncthreads();
    }

    // epilogue: C row = mf*16+lg*4+rr (m), col = w*32+nf*16+lq (n)
    const float osc = (wm == 0) ? QSCALE : 1.0f;
    if (wm < 2) {
        // retile [32 m][128 n] bf16 (row 256B, granule ^ row&7)
#pragma unroll
        for (int mf = 0; mf < 2; ++mf)
#pragma unroll
            for (int nf = 0; nf < 2; ++nf)
#pragma unroll
                for (int rr = 0; rr < 4; ++rr) {
                    const int row = mf * 16 + lg * 4 + rr;
                    const int col = w * 32 + nf * 16 + lq;
                    *(u16*)(smem + row * 256 + (((col >> 3) ^ (row & 7)) << 4) + ((col & 7) << 1))
                        = f2bf(acc[mf][nf][rr] * osc);
                }
        __syncthreads();
        u16* dst = (wm == 0 ? Qb : Kb) + (size_t)m0 * 128;
#pragma unroll
        for (int i = 0; i < 2; ++i) {
            const int j = i * 256 + tid;
            const int row = j >> 4, c = j & 15;
            *(short8*)(dst + (size_t)row * 128 + c * 8)
                = *(const short8*)(smem + row * 256 + ((c ^ (row & 7)) << 4));
        }
    } else {
        // V transposed: [128 d][32 s] bf16 (row 64B, granule s>>3 ^ (d&3))
#pragma unroll
        for (int mf = 0; mf < 2; ++mf)
#pragma unroll
            for (int nf = 0; nf < 2; ++nf)
#pragma unroll
                for (int rr = 0; rr < 4; ++rr) {
                    const int sl = mf * 16 + lg * 4 + rr;
                    const int d  = w * 32 + nf * 16 + lq;
                    *(u16*)(smem + d * 64 + (((sl >> 3) ^ (d & 3)) << 4) + ((sl & 7) << 1))
                        = f2bf(acc[mf][nf][rr]);
                }
        __syncthreads();
        const int b = m0 >> 11, s0b = m0 & 2047;
        u16* dst = Vtb + (size_t)b * DDIM * SEQ;
#pragma unroll
        for (int i = 0; i < 2; ++i) {
            const int j = i * 256 + tid;
            const int dd = j >> 2, c = j & 3;
            *(short8*)(dst + (size_t)dd * SEQ + s0b + c * 8)
                = *(const short8*)(smem + dd * 64 + ((c ^ (dd & 3)) << 4));
        }
    }
}

// ---------------- kernel 3: fused flash attention (swapped QK^T, reg-direct K/V) ---------
// 512 blocks (XCD-chunked), 4 waves; wave w owns kv quarter [w*512,(w+1)*512), KVB=32.
// S^T = mfma(K,Q): per-lane softmax (q=lq). O^T = mfma(V,P). No main-loop barriers.
__global__ __launch_bounds__(256, 2) void flash_kernel(
    const u32* __restrict__ Mb,
    const u16* __restrict__ Qb, const u16* __restrict__ Kb, const u16* __restrict__ Vtb,
    float* __restrict__ out)
{
    __shared__ __align__(16) uint8_t smem[36864];   // Ol 32KB @0, P 4x1KB @32768
    __shared__ float ml_m[4][16], ml_l[4][16], recipL[16];

    const int tid = threadIdx.x;
    const int w = tid >> 6, lane = tid & 63;
    const int lq = lane & 15, lg = lane >> 4;

    const int bid = blockIdx.x;
    const int qt = (bid & 7) * 64 + (bid >> 3);     // 64 contiguous q-tiles per XCD
    const int b = qt >> 7;
    const int q0 = (qt & 127) << 4;
    const size_t qrow0 = (size_t)b * SEQ + q0;

    const u16* Qp = Qb + qrow0 * 128;
    const u16* Kp = Kb + (size_t)b * SEQ * 128;
    const u16* Vp = Vtb + (size_t)b * DDIM * SEQ;
    const u32* mrp = Mb + (qrow0 + lq) * 64 + w * 16;

    // Q (B-operand): lane holds Q[q=lq][k=ks*32+lg*8 ..+8]
    short8 qf[4];
#pragma unroll
    for (int ks = 0; ks < 4; ++ks)
        qf[ks] = *(const short8*)(Qp + (size_t)lq * 128 + ks * 32 + lg * 8);

    f32x4 acc[8] = {};                  // O^T: acc[df][r] = O[q=lq][d=df*16+lg*4+r]
    float m = -1e30f, l = 0.0f;

    const int kv00 = w * 512;
    short8 kf[2][4], vf[8];
    u32 mw;
    // prologue: t=0 loads
#pragma unroll
    for (int nf = 0; nf < 2; ++nf)
#pragma unroll
        for (int ks = 0; ks < 4; ++ks)
            kf[nf][ks] = *(const short8*)(Kp + (size_t)(kv00 + nf * 16 + lq) * 128 + ks * 32 + lg * 8);
#pragma unroll
    for (int df = 0; df < 8; ++df)
        vf[df] = *(const short8*)(Vp + (size_t)(df * 16 + lq) * SEQ + kv00 + lg * 8);
    mw = mrp[0];

    uint8_t* pbase = smem + 32768 + w * 1024;       // P: [16 q][32 kv] bf16, 64B rows

#pragma unroll 1
    for (int t = 0; t < 16; ++t) {
        const int tn = (t < 15) ? t + 1 : 15;
        const int kvn = kv00 + tn * 32;
        __builtin_amdgcn_sched_barrier(0);
        // S^T = K Q : C row = kv (lg*4+r, +16nf), col = q (lq)
        f32x4 sacc[2] = {};
#pragma unroll
        for (int ks = 0; ks < 4; ++ks)
#pragma unroll
            for (int nf = 0; nf < 2; ++nf)
                sacc[nf] = __builtin_amdgcn_mfma_f32_16x16x32_bf16(kf[nf][ks], qf[ks], sacc[nf], 0, 0, 0);
        __builtin_amdgcn_sched_barrier(0);
        // prefetch K for next tile (WAR on kf is safe: MFMAs already issued)
#pragma unroll
        for (int nf = 0; nf < 2; ++nf)
#pragma unroll
            for (int ks = 0; ks < 4; ++ks)
                kf[nf][ks] = *(const short8*)(Kp + (size_t)(kvn + nf * 16 + lq) * 128 + ks * 32 + lg * 8);
        __builtin_amdgcn_sched_barrier(0);
        // per-lane softmax for q=lq over this tile's 32 kv
        float sv[2][4];
#pragma unroll
        for (int nf = 0; nf < 2; ++nf)
#pragma unroll
            for (int r = 0; r < 4; ++r)
                sv[nf][r] = sacc[nf][r] + (((mw >> (nf * 16 + lg * 4 + r)) & 1u) ? -1e15f : 0.0f);
        float tm = sv[0][0];
#pragma unroll
        for (int nf = 0; nf < 2; ++nf)
#pragma unroll
            for (int r = 0; r < 4; ++r) tm = fmaxf(tm, sv[nf][r]);
        tm = fmaxf(tm, __shfl_xor(tm, 16));
        tm = fmaxf(tm, __shfl_xor(tm, 32));
        const float mnew = fmaxf(m, tm);
        const float sf = __expf(m - mnew);
        m = mnew;
        float p[2][4];
        float rs = 0.0f;
#pragma unroll
        for (int nf = 0; nf < 2; ++nf)
#pragma unroll
            for (int r = 0; r < 4; ++r) { p[nf][r] = __expf(sv[nf][r] - m); rs += p[nf][r]; }
        rs += __shfl_xor(rs, 16);
        rs += __shfl_xor(rs, 32);
        l = l * sf + rs;
        mw = mrp[tn];                                   // prefetch next mask word
#pragma unroll
        for (int df = 0; df < 8; ++df) acc[df] *= sf;
        // P -> per-wave LDS [q=lq][kv], packed pairs (4 x ds_write_b32), swizzled granules
#pragma unroll
        for (int nf = 0; nf < 2; ++nf)
#pragma unroll
            for (int h = 0; h < 2; ++h) {
                const u32 pk = (u32)f2bf(p[nf][2 * h]) | ((u32)f2bf(p[nf][2 * h + 1]) << 16);
                const int kv = lg * 4 + 2 * h + 16 * nf;
                *(u32*)(pbase + lq * 64 + (((kv >> 3) ^ (lq & 3)) << 4) + ((kv << 1) & 15)) = pk;
            }
        // P (B-operand): lane needs P[kv=lg*8..+7][q=lq]
        const short8 pf = *(const short8*)(pbase + lq * 64 + ((lg ^ (lq & 3)) << 4));
        __builtin_amdgcn_sched_barrier(0);
        // O^T += V^T P : C row = d (lg*4+r within df), col = q (lq)
#pragma unroll
        for (int df = 0; df < 8; ++df)
            acc[df] = __builtin_amdgcn_mfma_f32_16x16x32_bf16(vf[df], pf, acc[df], 0, 0, 0);
        __builtin_amdgcn_sched_barrier(0);
        // prefetch V for next tile
#pragma unroll
        for (int df = 0; df < 8; ++df)
            vf[df] = *(const short8*)(Vp + (size_t)(df * 16 + lq) * SEQ + kvn + lg * 8);
    }

    // ---- combine 4 kv-quarters ----
    if (lg == 0) { ml_m[w][lq] = m; ml_l[w][lq] = l; }
    __syncthreads();
    {
        const float m0v = ml_m[0][lq], m1v = ml_m[1][lq], m2v = ml_m[2][lq], m3v = ml_m[3][lq];
        const float mm = fmaxf(fmaxf(m0v, m1v), fmaxf(m2v, m3v));
        const float Lg = ml_l[0][lq] * __expf(m0v - mm) + ml_l[1][lq] * __expf(m1v - mm)
                       + ml_l[2][lq] * __expf(m2v - mm) + ml_l[3][lq] * __expf(m3v - mm);
        const float s = __expf(m - mm);
        if (w == 0 && lg == 0) recipL[lq] = 1.0f / Lg;
        float* Ol = (float*)smem;                       // [4][16 q][128 d]
#pragma unroll
        for (int df = 0; df < 8; ++df) {
            const f32x4 vsc = acc[df] * s;
            *(f32x4*)(Ol + (size_t)(w * 16 + lq) * 128 + df * 16 + lg * 4) = vsc;
        }
    }
    __syncthreads();
    {
        const float* Ol = (const float*)smem;
        const int row = tid >> 4, c0 = (tid & 15) * 8;
        const float rl = recipL[row];
        f32x4 s0 = {}, s1 = {};
#pragma unroll
        for (int wv = 0; wv < 4; ++wv) {
            const float* p2 = Ol + (size_t)(wv * 16 + row) * 128 + c0;
            s0 += *(const f32x4*)p2;
            s1 += *(const f32x4*)(p2 + 4);
        }
        s0 *= rl; s1 *= rl;
        float* op = out + (qrow0 + row) * 128 + c0;
        *(f32x4*)op = s0;
        *(f32x4*)(op + 4) = s1;
    }
}

// ---------------- launcher ---------------------------------------------------------------
extern "C" void kernel_launch(void* const* d_in, const int* in_sizes, int n_in,
                              void* d_out, int out_size, void* d_ws, size_t ws_size,
                              hipStream_t stream) {
    (void)in_sizes; (void)n_in; (void)out_size; (void)ws_size;
    const float* inputs = (const float*)d_in[0];
    const int*   mask   = (const int*)d_in[1];
    const float* Wq     = (const float*)d_in[2];
    const float* Wk     = (const float*)d_in[3];
    const float* Wv     = (const float*)d_in[4];
    float* out = (float*)d_out;

    uint8_t* ws = (uint8_t*)d_ws;
    u16* Wtb   = (u16*)ws;                     //   786,432 B [3][128][1024] bf16
    u16* Qb    = (u16*)(ws + 786432);          // 2,097,152 B [8192][128] bf16 (pre-scaled)
    u16* Kb    = (u16*)(ws + 2883584);         // 2,097,152 B
    u16* Vtb   = (u16*)(ws + 4980736);         // 2,097,152 B [4][128][2048] bf16
    u32* Mbits = (u32*)(ws + 7077888);         // 2,097,152 B [4*2048][64] u32
    // total ws use: 9,175,040 B

    hipLaunchKernelGGL(prep_kernel, dim3(2144), dim3(256), 0, stream, mask, Wq, Wk, Wv, Mbits, Wtb);
    hipLaunchKernelGGL(proj_kernel, dim3(768), dim3(256), 0, stream, inputs, Wtb, Qb, Kb, Vtb);
    hipLaunchKernelGGL(flash_kernel, dim3(512), dim3(256), 0, stream, Mbits, Qb, Kb, Vtb, out);
}

// Round 4
// 170.290 us; speedup vs baseline: 1.1915x; 1.1915x over previous
//
#include <hip/hip_runtime.h>
#include <stdint.h>

// AttentionHead: out = softmax(QK^T/sqrt(dk) - 1e15*mask) @ V, Q/K/V = inputs @ W{q,k,v}
// B=4 S=2048 E=1024 D=128. bf16 MFMA; swapped-QK^T flash, shared-tile double-buffered LDS.

#define SEQ   2048
#define EDIM  1024
#define DDIM  128
#define QSCALE 0.08838834764831845f   // 1/sqrt(128)

typedef unsigned short u16;
typedef unsigned int   u32;
using short8 = __attribute__((ext_vector_type(8))) short;   // 8 x bf16 (4 VGPR) MFMA frag
using f32x4  = __attribute__((ext_vector_type(4))) float;
using int4v  = __attribute__((ext_vector_type(4))) int;

__device__ __forceinline__ u16 f2bf(float x) {              // f32 -> bf16 RNE
    uint32_t u = __float_as_uint(x);
    return (u16)((u + 0x7fffu + ((u >> 16) & 1u)) >> 16);
}

// async global->LDS 16B per lane; LDS dst = wave-uniform base + lane*16 (linear).
__device__ __forceinline__ void gld16(const void* gsrc, void* lds_dst) {
    __builtin_amdgcn_global_load_lds(
        (const __attribute__((address_space(1))) uint32_t*)(uintptr_t)gsrc,
        (__attribute__((address_space(3))) uint32_t*)(uint32_t)(uintptr_t)lds_dst,
        16, 0, 0);
}

// ---------------- kernel 1: prep = mask bit-pack (coalesced) + W transpose ---------------
__global__ __launch_bounds__(256) void prep_kernel(
    const int* __restrict__ mask,
    const float* __restrict__ Wq, const float* __restrict__ Wk, const float* __restrict__ Wv,
    u32* __restrict__ Mbits, u16* __restrict__ Wt)
{
    __shared__ u32 nib32[2048];
    __shared__ u16 tl[64][65];
    const int bx = blockIdx.x;
    const int tid = threadIdx.x;
    if (bx < 2048) {
        const int* src = mask + (size_t)bx * 8192;
#pragma unroll
        for (int it = 0; it < 8; ++it) {
            const int idx = it * 256 + tid;
            const int4v v = *(const int4v*)(src + idx * 4);
            const u32 nb = (v[0] != 0 ? 1u : 0u) | (v[1] != 0 ? 2u : 0u)
                         | (v[2] != 0 ? 4u : 0u) | (v[3] != 0 ? 8u : 0u);
            nib32[(idx & 7) * 256 + ((idx >> 3) ^ ((idx & 7) << 2))] = nb;
        }
        __syncthreads();
        u32 word = 0;
#pragma unroll
        for (int j = 0; j < 8; ++j)
            word |= (nib32[j * 256 + (tid ^ (j << 2))] & 0xFu) << (4 * j);
        Mbits[bx * 256 + tid] = word;
    } else {
        const int t = bx - 2048;
        const int wsel = t >> 5;
        const int tile = t & 31;
        const int k0 = (tile >> 1) * 64;
        const int n0 = (tile & 1) * 64;
        const float* W = (wsel == 0) ? Wq : ((wsel == 1) ? Wk : Wv);
#pragma unroll
        for (int it = 0; it < 16; ++it) {
            const int idx = it * 256 + tid;
            const int r = idx >> 6, c = idx & 63;
            tl[c][r] = f2bf(W[(size_t)(k0 + r) * DDIM + n0 + c]);
        }
        __syncthreads();
        u16* Wtp = Wt + (size_t)wsel * DDIM * EDIM;
#pragma unroll
        for (int it = 0; it < 16; ++it) {
            const int idx = it * 256 + tid;
            const int r = idx >> 6, c = idx & 63;
            Wtp[(size_t)(n0 + r) * EDIM + k0 + c] = tl[r][c];
        }
    }
}

// ---------------- kernel 2: projections. 768 blocks, tile 32m x 128n, BK=64 --------------
__global__ __launch_bounds__(256, 3) void proj_kernel(
    const float* __restrict__ Ain, const u16* __restrict__ Wtb,
    u16* __restrict__ Qb, u16* __restrict__ Kb, u16* __restrict__ Vtb)
{
    __shared__ __align__(16) uint8_t smem[20480];
    const int tid = threadIdx.x;
    const int w = tid >> 6, lane = tid & 63;
    const int lq = lane & 15, lg = lane >> 4;

    const int bid = blockIdx.x;
    const int wg = (bid & 7) * 96 + (bid >> 3);
    const int wm = wg % 3;
    const int m0 = (wg / 3) * 32;
    const u16* Wt = Wtb + (size_t)wm * DDIM * EDIM;

    f32x4 acc[2][2] = {};

#pragma unroll 1
    for (int kt = 0; kt < 16; ++kt) {
        const int k0 = kt * 64;
#pragma unroll
        for (int i = 0; i < 4; ++i) {
            const int G = i * 256 + tid;
            const int n = G >> 3, c = G & 7;
            gld16(Wt + (size_t)n * EDIM + k0 + ((c ^ (n & 7)) << 3),
                  smem + 4096 + i * 4096 + w * 1024);
        }
        {
            const int row = tid >> 3, c = tid & 7;
            const float* s2 = Ain + (size_t)(m0 + row) * EDIM + k0 + ((c ^ (row & 7)) << 3);
            const f32x4 a0 = *(const f32x4*)s2;
            const f32x4 a1 = *(const f32x4*)(s2 + 4);
            short8 v;
            v[0] = (short)f2bf(a0[0]); v[1] = (short)f2bf(a0[1]);
            v[2] = (short)f2bf(a0[2]); v[3] = (short)f2bf(a0[3]);
            v[4] = (short)f2bf(a1[0]); v[5] = (short)f2bf(a1[1]);
            v[6] = (short)f2bf(a1[2]); v[7] = (short)f2bf(a1[3]);
            *(short8*)(smem + row * 128 + (c << 4)) = v;
        }
        __syncthreads();
#pragma unroll
        for (int ks = 0; ks < 2; ++ks) {
            short8 af[2], bfv[2];
#pragma unroll
            for (int mf = 0; mf < 2; ++mf) {
                const int arow = mf * 16 + lq;
                af[mf] = *(const short8*)(smem + arow * 128 + ((((ks << 2) + lg) ^ (arow & 7)) << 4));
            }
#pragma unroll
            for (int nf = 0; nf < 2; ++nf) {
                const int brow = w * 32 + nf * 16 + lq;
                bfv[nf] = *(const short8*)(smem + 4096 + brow * 128 + ((((ks << 2) + lg) ^ (brow & 7)) << 4));
            }
#pragma unroll
            for (int mf = 0; mf < 2; ++mf)
#pragma unroll
                for (int nf = 0; nf < 2; ++nf)
                    acc[mf][nf] = __builtin_amdgcn_mfma_f32_16x16x32_bf16(af[mf], bfv[nf], acc[mf][nf], 0, 0, 0);
        }
        __syncthreads();
    }

    const float osc = (wm == 0) ? QSCALE : 1.0f;
    if (wm < 2) {
#pragma unroll
        for (int mf = 0; mf < 2; ++mf)
#pragma unroll
            for (int nf = 0; nf < 2; ++nf)
#pragma unroll
                for (int rr = 0; rr < 4; ++rr) {
                    const int row = mf * 16 + lg * 4 + rr;
                    const int col = w * 32 + nf * 16 + lq;
                    *(u16*)(smem + row * 256 + (((col >> 3) ^ (row & 7)) << 4) + ((col & 7) << 1))
                        = f2bf(acc[mf][nf][rr] * osc);
                }
        __syncthreads();
        u16* dst = (wm == 0 ? Qb : Kb) + (size_t)m0 * 128;
#pragma unroll
        for (int i = 0; i < 2; ++i) {
            const int j = i * 256 + tid;
            const int row = j >> 4, c = j & 15;
            *(short8*)(dst + (size_t)row * 128 + c * 8)
                = *(const short8*)(smem + row * 256 + ((c ^ (row & 7)) << 4));
        }
    } else {
#pragma unroll
        for (int mf = 0; mf < 2; ++mf)
#pragma unroll
            for (int nf = 0; nf < 2; ++nf)
#pragma unroll
                for (int rr = 0; rr < 4; ++rr) {
                    const int sl = mf * 16 + lg * 4 + rr;
                    const int d  = w * 32 + nf * 16 + lq;
                    *(u16*)(smem + d * 64 + (((sl >> 3) ^ (d & 3)) << 4) + ((sl & 7) << 1))
                        = f2bf(acc[mf][nf][rr]);
                }
        __syncthreads();
        const int b = m0 >> 11, s0b = m0 & 2047;
        u16* dst = Vtb + (size_t)b * DDIM * SEQ;
#pragma unroll
        for (int i = 0; i < 2; ++i) {
            const int j = i * 256 + tid;
            const int dd = j >> 2, c = j & 3;
            *(short8*)(dst + (size_t)dd * SEQ + s0b + c * 8)
                = *(const short8*)(smem + dd * 64 + ((c ^ (dd & 3)) << 4));
        }
    }
}

// ---------------- kernel 3: fused flash attention ----------------------------------------
// 256 blocks x 512 thr (8 waves = qi{0,1} x ki{0..3}). Block = 32 q-rows; wave = 16 q x
// 512 kv quarter, KVB=32, 16 iters. K/V tile per ki shared by qi-pair: qi=0 stages K,
// qi=1 stages V (8 gld16 each). Double-buffered LDS; one barrier/iter, loads in flight.
__global__ __launch_bounds__(512, 1) void flash_kernel(
    const u32* __restrict__ Mb,
    const u16* __restrict__ Qb, const u16* __restrict__ Kb, const u16* __restrict__ Vtb,
    float* __restrict__ out)
{
    __shared__ __align__(16) uint8_t smem[139264];  // KV [4 ki][2 buf][K 8KB|V 8KB] @0, P [8][1KB] @131072
    __shared__ float ml_m[2][4][16], ml_l[2][4][16], recipL[32];

    const int tid = threadIdx.x;
    const int w = tid >> 6, lane = tid & 63;
    const int qi = w >> 2, ki = w & 3;
    const int lq = lane & 15, lg = lane >> 4;

    const int bid = blockIdx.x;
    const int qt = (bid & 7) * 32 + (bid >> 3);     // XCD-chunked: 32 contiguous q-tiles/XCD
    const int b = qt >> 6;
    const int q0 = (qt & 63) << 5;
    const size_t qrow0 = (size_t)b * SEQ + q0;

    const u16* Qp = Qb + (qrow0 + qi * 16) * 128;
    const u16* Kp = Kb + (size_t)b * SEQ * 128;
    const u16* Vp = Vtb + (size_t)b * DDIM * SEQ;
    const u32* mrp = Mb + (qrow0 + qi * 16 + lq) * 64 + ki * 16;

    // Q (B-operand): lane holds Q[q=lq][k=ks*32+lg*8 ..+8] (pre-scaled by 1/sqrt(dk))
    short8 qf[4];
#pragma unroll
    for (int ks = 0; ks < 4; ++ks)
        qf[ks] = *(const short8*)(Qp + (size_t)lq * 128 + ks * 32 + lg * 8);

    f32x4 acc[8] = {};                  // O^T: acc[df][r] = O[q=lq][d=df*16+lg*4+r]
    float m = -1e30f, l = 0.0f;

    uint8_t* kvb0 = smem + ki * 32768;              // [2 buf][16KB]
    uint8_t* pbase = smem + 131072 + w * 1024;      // P: [16 q][32 kv] bf16

    // staging: wave qi=0 -> K tile [32 kv][128 d]; qi=1 -> V tile [128 d][32 kv]
    auto stage = [&](uint8_t* kvb, int kv0) {
        if (qi == 0) {
#pragma unroll
            for (int i = 0; i < 8; ++i) {
                const int G = i * 64 + lane;
                const int row = G >> 4, c = G & 15;
                gld16(Kp + (size_t)(kv0 + row) * 128 + ((c ^ (row & 7)) << 3),
                      kvb + i * 1024);
            }
        } else {
#pragma unroll
            for (int i = 0; i < 8; ++i) {
                const int G = i * 64 + lane;
                const int dd = G >> 2, c = G & 3;
                gld16(Vp + (size_t)dd * SEQ + kv0 + ((c ^ ((dd ^ (dd >> 2)) & 3)) << 3),
                      kvb + 8192 + i * 1024);
            }
        }
    };

    // prologue
    stage(kvb0, ki * 512);
    u32 mw = mrp[0];
    asm volatile("s_waitcnt vmcnt(0)" ::: "memory");
    __builtin_amdgcn_s_barrier();

#pragma unroll 1
    for (int t = 0; t < 16; ++t) {
        uint8_t* kvb = kvb0 + (t & 1) * 16384;
        if (t < 15) stage(kvb0 + ((t + 1) & 1) * 16384, ki * 512 + (t + 1) * 32);
        const u32 mwn = mrp[(t < 15) ? t + 1 : 15];     // prefetch next mask word
        __builtin_amdgcn_sched_barrier(0);

        // S^T = K Q : C row = kv (nf*16+lg*4+r), col = q (lq)
        f32x4 sacc[2] = {};
        __builtin_amdgcn_s_setprio(1);
#pragma unroll
        for (int ks = 0; ks < 4; ++ks)
#pragma unroll
            for (int nf = 0; nf < 2; ++nf) {
                const int krow = nf * 16 + lq;
                const short8 kf = *(const short8*)(kvb + krow * 256 + ((((ks << 2) + lg) ^ (krow & 7)) << 4));
                sacc[nf] = __builtin_amdgcn_mfma_f32_16x16x32_bf16(kf, qf[ks], sacc[nf], 0, 0, 0);
            }
        __builtin_amdgcn_s_setprio(0);

        // per-lane online softmax for q=lq over 32 kv
        float sv[2][4];
#pragma unroll
        for (int nf = 0; nf < 2; ++nf)
#pragma unroll
            for (int r = 0; r < 4; ++r)
                sv[nf][r] = sacc[nf][r] + (((mw >> (nf * 16 + lg * 4 + r)) & 1u) ? -1e15f : 0.0f);
        float tm = sv[0][0];
#pragma unroll
        for (int nf = 0; nf < 2; ++nf)
#pragma unroll
            for (int r = 0; r < 4; ++r) tm = fmaxf(tm, sv[nf][r]);
        tm = fmaxf(tm, __shfl_xor(tm, 16));
        tm = fmaxf(tm, __shfl_xor(tm, 32));
        if (!__all(tm <= m + 8.0f)) {                   // defer-max: rescale rarely
            const float mnew = fmaxf(m, tm);
            const float sf = __expf(m - mnew);
            m = mnew;
            l *= sf;
#pragma unroll
            for (int df = 0; df < 8; ++df) acc[df] *= sf;
        }
        float p[2][4];
        float rs = 0.0f;
#pragma unroll
        for (int nf = 0; nf < 2; ++nf)
#pragma unroll
            for (int r = 0; r < 4; ++r) { p[nf][r] = __expf(sv[nf][r] - m); rs += p[nf][r]; }
        rs += __shfl_xor(rs, 16);
        rs += __shfl_xor(rs, 32);
        l += rs;
        mw = mwn;

        // P -> per-wave LDS [q=lq][32 kv] via v_cvt_pk_bf16_f32 (4 x ds_write_b32)
#pragma unroll
        for (int nf = 0; nf < 2; ++nf)
#pragma unroll
            for (int h = 0; h < 2; ++h) {
                u32 pk;
                asm("v_cvt_pk_bf16_f32 %0, %1, %2" : "=v"(pk) : "v"(p[nf][2 * h]), "v"(p[nf][2 * h + 1]));
                const int kv = nf * 16 + lg * 4 + 2 * h;
                *(u32*)(pbase + lq * 64 + (((kv >> 3) ^ (lq & 3)) << 4) + ((kv << 1) & 15)) = pk;
            }
        // P (B-operand): lane needs P[kv=lg*8..+8][q=lq]
        const short8 pf = *(const short8*)(pbase + lq * 64 + ((lg ^ (lq & 3)) << 4));

        // O^T += V^T P
        __builtin_amdgcn_s_setprio(1);
#pragma unroll
        for (int df = 0; df < 8; ++df) {
            const int dd = df * 16 + lq;
            const short8 vf = *(const short8*)(kvb + 8192 + dd * 64 + ((lg ^ ((dd ^ (dd >> 2)) & 3)) << 4));
            acc[df] = __builtin_amdgcn_mfma_f32_16x16x32_bf16(vf, pf, acc[df], 0, 0, 0);
        }
        __builtin_amdgcn_s_setprio(0);

        asm volatile("s_waitcnt vmcnt(0)" ::: "memory");   // own stage loads done (1 iter old)
        __builtin_amdgcn_s_barrier();                       // partner's too -> next buf ready
    }

    // ---- combine 4 kv-quarters per qi ----
    if (lg == 0) { ml_m[qi][ki][lq] = m; ml_l[qi][ki][lq] = l; }
    __syncthreads();
    {
        const float m0v = ml_m[qi][0][lq], m1v = ml_m[qi][1][lq];
        const float m2v = ml_m[qi][2][lq], m3v = ml_m[qi][3][lq];
        const float mm = fmaxf(fmaxf(m0v, m1v), fmaxf(m2v, m3v));
        const float Lg = ml_l[qi][0][lq] * __expf(m0v - mm) + ml_l[qi][1][lq] * __expf(m1v - mm)
                       + ml_l[qi][2][lq] * __expf(m2v - mm) + ml_l[qi][3][lq] * __expf(m3v - mm);
        if (ki == 0 && lg == 0) recipL[qi * 16 + lq] = 1.0f / Lg;
        const float s = __expf(m - mm);
        float* Ol = (float*)smem;                       // [2 qi][4 ki][16 q][132] f32
        float* dstq = Ol + ((size_t)(qi * 4 + ki) * 16 + lq) * 132;
#pragma unroll
        for (int df = 0; df < 8; ++df) {
            const f32x4 vsc = acc[df] * s;
            *(f32x4*)(dstq + df * 16 + lg * 4) = vsc;
        }
    }
    __syncthreads();
    {
        const float* Ol = (const float*)smem;
        const int row = tid >> 4, c0 = (tid & 15) * 8;  // row 0..31
        const int rqi = row >> 4, rq = row & 15;
        const float rl = recipL[row];
        f32x4 s0 = {}, s1 = {};
#pragma unroll
        for (int kk = 0; kk < 4; ++kk) {
            const float* p2 = Ol + ((size_t)(rqi * 4 + kk) * 16 + rq) * 132 + c0;
            s0 += *(const f32x4*)p2;
            s1 += *(const f32x4*)(p2 + 4);
        }
        s0 *= rl; s1 *= rl;
        float* op = out + (qrow0 + row) * 128 + c0;
        *(f32x4*)op = s0;
        *(f32x4*)(op + 4) = s1;
    }
}

// ---------------- launcher ---------------------------------------------------------------
extern "C" void kernel_launch(void* const* d_in, const int* in_sizes, int n_in,
                              void* d_out, int out_size, void* d_ws, size_t ws_size,
                              hipStream_t stream) {
    (void)in_sizes; (void)n_in; (void)out_size; (void)ws_size;
    const float* inputs = (const float*)d_in[0];
    const int*   mask   = (const int*)d_in[1];
    const float* Wq     = (const float*)d_in[2];
    const float* Wk     = (const float*)d_in[3];
    const float* Wv     = (const float*)d_in[4];
    float* out = (float*)d_out;

    uint8_t* ws = (uint8_t*)d_ws;
    u16* Wtb   = (u16*)ws;                     //   786,432 B [3][128][1024] bf16
    u16* Qb    = (u16*)(ws + 786432);          // 2,097,152 B [8192][128] bf16 (pre-scaled)
    u16* Kb    = (u16*)(ws + 2883584);         // 2,097,152 B
    u16* Vtb   = (u16*)(ws + 4980736);         // 2,097,152 B [4][128][2048] bf16
    u32* Mbits = (u32*)(ws + 7077888);         // 2,097,152 B [4*2048][64] u32
    // total ws use: 9,175,040 B

    hipLaunchKernelGGL(prep_kernel, dim3(2144), dim3(256), 0, stream, mask, Wq, Wk, Wv, Mbits, Wtb);
    hipLaunchKernelGGL(proj_kernel, dim3(768), dim3(256), 0, stream, inputs, Wtb, Qb, Kb, Vtb);
    hipLaunchKernelGGL(flash_kernel, dim3(256), dim3(512), 0, stream, Mbits, Qb, Kb, Vtb, out);
}